// Round 1
// baseline (178.813 us; speedup 1.0000x reference)
//
#include <hip/hip_runtime.h>

// Quanvolutional layer: 8-qubit statevector sim per (patch, out_channel).
// One wave = one circuit. State: 256 complex amps = 4 complex per lane.
// Flat amp index = lane*4 + r ; qubit q lives on flat bit (7-q):
//   qubits 0..5 -> lane bits 5..0 (cross-lane via shfl_xor)
//   qubit  6    -> r bit 1, qubit 7 -> r bit 0 (in-register)

namespace {

__global__ __launch_bounds__(256) void qconv_kernel(
    const float* __restrict__ x,     // (2, 2, 128, 128) fp32
    const float* __restrict__ wts,   // (4, 4, 8) fp32
    float* __restrict__ out)         // (2, 4, 64, 64) fp32
{
  const int lane = threadIdx.x & 63;
  const int wave = threadIdx.x >> 6;
  const int circuit = blockIdx.x * 4 + wave;   // 32768 circuits
  const int oc    = circuit & 3;
  const int patch = circuit >> 2;
  const int b  = patch >> 12;
  const int ph = (patch >> 6) & 63;
  const int pw = patch & 63;

  // ---- load the 8 embedding angles: x[b, c, 2*ph+dh, 2*pw+dw], q = c*4+dh*2+dw
  float cth[8], sth[8];
#pragma unroll
  for (int c = 0; c < 2; ++c)
#pragma unroll
    for (int dh = 0; dh < 2; ++dh)
#pragma unroll
      for (int dw = 0; dw < 2; ++dw) {
        float th = x[((b * 2 + c) * 128 + (2 * ph + dh)) * 128 + (2 * pw + dw)];
        int q = c * 4 + dh * 2 + dw;
        __sincosf(0.5f * th, &sth[q], &cth[q]);
      }

  // ---- embed of |0..0> is a product state: amp(idx) = prod_q (bit? s_q : c_q) * (-i)^popc(idx)
  float sr[4], si[4];
#pragma unroll
  for (int r = 0; r < 4; ++r) {
    const int idx = lane * 4 + r;
    float m = 1.0f;
#pragma unroll
    for (int q = 0; q < 8; ++q)
      m *= ((idx >> (7 - q)) & 1) ? sth[q] : cth[q];
    const int pm = __popc(idx) & 3;
    sr[r] = (pm == 0) ? m : ((pm == 2) ? -m : 0.0f);
    si[r] = (pm == 1) ? -m : ((pm == 3) ? m : 0.0f);
  }

  // ---- 4 entangling layers ----
  const float* wc = wts + oc * 32;
#pragma unroll
  for (int l = 0; l < 4; ++l) {
    // RX(w[l][q]) on every qubit. Pair-symmetric update:
    //   new_r = c*r + s*partner_i ; new_i = c*i - s*partner_r
#pragma unroll
    for (int q = 0; q < 8; ++q) {
      float s, c;
      __sincosf(0.5f * wc[l * 8 + q], &s, &c);
      const int tb = 7 - q;                    // flat bit of this qubit
      if (tb >= 2) {                           // cross-lane
        const int mask = 1 << (tb - 2);
#pragma unroll
        for (int r = 0; r < 4; ++r) {
          float pr = __shfl_xor(sr[r], mask, 64);
          float pi = __shfl_xor(si[r], mask, 64);
          float nr = c * sr[r] + s * pi;
          float ni = c * si[r] - s * pr;
          sr[r] = nr; si[r] = ni;
        }
      } else if (tb == 1) {                    // in-lane pairs (0,2),(1,3)
#pragma unroll
        for (int r = 0; r < 2; ++r) {
          float ar = sr[r], ai = si[r], br = sr[r + 2], bi = si[r + 2];
          sr[r]     = c * ar + s * bi;  si[r]     = c * ai - s * br;
          sr[r + 2] = c * br + s * ai;  si[r + 2] = c * bi - s * ar;
        }
      } else {                                 // tb==0: in-lane pairs (0,1),(2,3)
#pragma unroll
        for (int r = 0; r < 4; r += 2) {
          float ar = sr[r], ai = si[r], br = sr[r + 1], bi = si[r + 1];
          sr[r]     = c * ar + s * bi;  si[r]     = c * ai - s * br;
          sr[r + 1] = c * br + s * ai;  si[r + 1] = c * bi - s * ar;
        }
      }
    }

    // CNOT ring q -> (q+1)%8. Flat bits: ctrl = 7-q, tgt = 6-q (mod 8).
    // q=0..4: ctrl lane bit (5-q), tgt lane bit (4-q): conditional cross-lane swap.
#pragma unroll
    for (int q = 0; q < 5; ++q) {
      const int mask  = 1 << (4 - q);
      const bool cond = (lane >> (5 - q)) & 1;
#pragma unroll
      for (int r = 0; r < 4; ++r) {
        float pr = __shfl_xor(sr[r], mask, 64);
        float pi = __shfl_xor(si[r], mask, 64);
        sr[r] = cond ? pr : sr[r];
        si[r] = cond ? pi : si[r];
      }
    }
    {   // q=5: ctrl lane bit0, tgt r-bit1: swap (0<->2),(1<->3) where lane&1
      const bool cond = lane & 1;
#pragma unroll
      for (int r = 0; r < 2; ++r) {
        float ar = sr[r], ai = si[r], br = sr[r + 2], bi = si[r + 2];
        sr[r]     = cond ? br : ar;  si[r]     = cond ? bi : ai;
        sr[r + 2] = cond ? ar : br;  si[r + 2] = cond ? ai : bi;
      }
    }
    {   // q=6: ctrl r-bit1, tgt r-bit0: swap amps r=2 <-> r=3 (register rename)
      float t;
      t = sr[2]; sr[2] = sr[3]; sr[3] = t;
      t = si[2]; si[2] = si[3]; si[3] = t;
    }
    {   // q=7: ctrl r-bit0, tgt lane bit5: unconditional swap of odd-r amps across lane^32
      sr[1] = __shfl_xor(sr[1], 32, 64);
      si[1] = __shfl_xor(si[1], 32, 64);
      sr[3] = __shfl_xor(sr[3], 32, 64);
      si[3] = __shfl_xor(si[3], 32, 64);
    }
  }

  // ---- <Z> on qubit 7 (flat bit 0): +|amp|^2 for even r, - for odd r ----
  float e = (sr[0] * sr[0] + si[0] * si[0]) - (sr[1] * sr[1] + si[1] * si[1])
          + (sr[2] * sr[2] + si[2] * si[2]) - (sr[3] * sr[3] + si[3] * si[3]);
#pragma unroll
  for (int off = 32; off > 0; off >>= 1)
    e += __shfl_xor(e, off, 64);

  if (lane == 0)
    out[((b * 4 + oc) * 64 + ph) * 64 + pw] = e;
}

} // namespace

extern "C" void kernel_launch(void* const* d_in, const int* in_sizes, int n_in,
                              void* d_out, int out_size, void* d_ws, size_t ws_size,
                              hipStream_t stream) {
  const float* x   = (const float*)d_in[0];   // 2*2*128*128 = 65536
  const float* wts = (const float*)d_in[1];   // 4*4*8 = 128
  float* out = (float*)d_out;                 // 2*4*64*64 = 32768
  // 32768 circuits, one wave each, 4 waves per block
  qconv_kernel<<<8192, 256, 0, stream>>>(x, wts, out);
}

// Round 2
// 132.371 us; speedup vs baseline: 1.3508x; 1.3508x over previous
//
#include <hip/hip_runtime.h>

// Quanvolutional layer: 8-qubit statevector sim per (patch, out_channel).
// One wave = one circuit. 256 complex amps = 4 complex per lane.
// Flat stored index j = lane*4 + r.
//
// Key trick: the CNOT ring is a GF(2)-linear index permutation F. We never
// move data for it; we keep the state array fixed and track P = F^l. An RX
// on qubit q (psi-bit b=7-q) at layer l then pairs stored indices j and
// j ^ v where v = F^{-l} e_b. Partner fetch = shfl_xor(state[r^vR], vL).
// Final <Z_7> sign = parity(F^4 j)_bit0 = parity(j & 0x88) -> lane bits 1,5.
//
// Direction masks M_l[b] (v for psi-bit b after l chains), computed from
// F^{-1} columns C = {0xC1,0x03,0x06,0x0C,0x18,0x30,0x60,0xC0}:
//   l=0: e_b
//   l=1: C0,C7,60,30,18,0C,06,03,C1  (per qubit q=0..7: 0xC0,0x60,0x30,0x18,0x0C,0x06,0x03,0xC1)
//   l=2: 0xA0,0x50,0x28,0x14,0x0A,0x05,0xC2,0x61
//   l=3: 0xF0,0x78,0x3C,0x1E,0x0F,0xC7,0xA3,0x91

namespace {

template<int VL, int VR>
__device__ __forceinline__ void rx_dir(float (&sr)[4], float (&si)[4],
                                       float c, float s) {
  if constexpr (VL != 0) {
    float pr[4], pi[4];
#pragma unroll
    for (int r = 0; r < 4; ++r) {
      pr[r] = __shfl_xor(sr[r ^ VR], VL, 64);
      pi[r] = __shfl_xor(si[r ^ VR], VL, 64);
    }
#pragma unroll
    for (int r = 0; r < 4; ++r) {
      float nr = c * sr[r] + s * pi[r];
      float ni = c * si[r] - s * pr[r];
      sr[r] = nr; si[r] = ni;
    }
  } else {
    // in-register pairing r <-> r^VR; symmetric update via temps
    float nr[4], ni[4];
#pragma unroll
    for (int r = 0; r < 4; ++r) {
      nr[r] = c * sr[r] + s * si[r ^ VR];
      ni[r] = c * si[r] - s * sr[r ^ VR];
    }
#pragma unroll
    for (int r = 0; r < 4; ++r) { sr[r] = nr[r]; si[r] = ni[r]; }
  }
}

// Fused RX(v1=(VL, vR=0), th1) * RX(v2=(VL, vR=1), th2): one shfl set serves both.
// A'[j] = c1c2 A[j] - i s1c2 A[j^v1] - i s2c1 A[j^v2] - s1s2 A[j^v1^v2]
// j^v1 = (lane^VL, r), j^v2 = (lane^VL, r^1), j^v1^v2 = (lane, r^1).
template<int VL>
__device__ __forceinline__ void rx_fused01(float (&sr)[4], float (&si)[4],
                                           float c1, float s1,
                                           float c2, float s2) {
  float qr[4], qi[4];
#pragma unroll
  for (int r = 0; r < 4; ++r) {
    qr[r] = __shfl_xor(sr[r], VL, 64);
    qi[r] = __shfl_xor(si[r], VL, 64);
  }
  const float cc = c1 * c2, a1 = s1 * c2, a2 = s2 * c1, ss = s1 * s2;
  float nr[4], ni[4];
#pragma unroll
  for (int r = 0; r < 4; ++r) {
    nr[r] = cc * sr[r] + a1 * qi[r] + a2 * qi[r ^ 1] - ss * sr[r ^ 1];
    ni[r] = cc * si[r] - a1 * qr[r] - a2 * qr[r ^ 1] - ss * si[r ^ 1];
  }
#pragma unroll
  for (int r = 0; r < 4; ++r) { sr[r] = nr[r]; si[r] = ni[r]; }
}

__global__ __launch_bounds__(256) void qconv_kernel(
    const float* __restrict__ x,     // (2, 2, 128, 128) fp32
    const float* __restrict__ wts,   // (4, 4, 8) fp32
    float* __restrict__ out)         // (2, 4, 64, 64) fp32
{
  const int lane = threadIdx.x & 63;
  const int wave = threadIdx.x >> 6;
  const int circuit = blockIdx.x * 4 + wave;   // 32768 circuits
  const int oc    = circuit & 3;
  const int patch = circuit >> 2;
  const int b  = patch >> 12;
  const int ph = (patch >> 6) & 63;
  const int pw = patch & 63;

  // ---- embedding angles: x[b, c, 2*ph+dh, 2*pw+dw], q = c*4 + dh*2 + dw
  float cth[8], sth[8];
#pragma unroll
  for (int c = 0; c < 2; ++c)
#pragma unroll
    for (int dh = 0; dh < 2; ++dh)
#pragma unroll
      for (int dw = 0; dw < 2; ++dw) {
        float th = x[((b * 2 + c) * 128 + (2 * ph + dh)) * 128 + (2 * pw + dw)];
        int q = c * 4 + dh * 2 + dw;
        __sincosf(0.5f * th, &sth[q], &cth[q]);
      }

  // ---- embed of |0..0> is a product state:
  //      amp(idx) = prod_q (bit? s_q : c_q) * (-i)^popc(idx)
  float sr[4], si[4];
#pragma unroll
  for (int r = 0; r < 4; ++r) {
    const int idx = lane * 4 + r;
    float m = 1.0f;
#pragma unroll
    for (int q = 0; q < 8; ++q)
      m *= ((idx >> (7 - q)) & 1) ? sth[q] : cth[q];
    const int pm = __popc(idx) & 3;
    sr[r] = (pm == 0) ? m : ((pm == 2) ? -m : 0.0f);
    si[r] = (pm == 1) ? -m : ((pm == 3) ? m : 0.0f);
  }

  const float* wc = wts + oc * 32;

#define RXG(MASK, ANG)                                              \
  do {                                                              \
    float s_, c_;                                                   \
    __sincosf(0.5f * (ANG), &s_, &c_);                              \
    rx_dir<((MASK) >> 2), ((MASK) & 3)>(sr, si, c_, s_);            \
  } while (0)

  // ---- layer 0: directions e_{7-q}
  RXG(0x80, wc[0]); RXG(0x40, wc[1]); RXG(0x20, wc[2]); RXG(0x10, wc[3]);
  RXG(0x08, wc[4]); RXG(0x04, wc[5]); RXG(0x02, wc[6]); RXG(0x01, wc[7]);

  // ---- layer 1: q0 (0xC0) and q7 (0xC1) share lane-mask 0x30 -> fused
  {
    float s1, c1, s2, c2;
    __sincosf(0.5f * wc[8],  &s1, &c1);
    __sincosf(0.5f * wc[15], &s2, &c2);
    rx_fused01<0x30>(sr, si, c1, s1, c2, s2);
  }
  RXG(0x60, wc[9]);  RXG(0x30, wc[10]); RXG(0x18, wc[11]);
  RXG(0x0C, wc[12]); RXG(0x06, wc[13]); RXG(0x03, wc[14]);

  // ---- layer 2
  RXG(0xA0, wc[16]); RXG(0x50, wc[17]); RXG(0x28, wc[18]); RXG(0x14, wc[19]);
  RXG(0x0A, wc[20]); RXG(0x05, wc[21]); RXG(0xC2, wc[22]); RXG(0x61, wc[23]);

  // ---- layer 3
  RXG(0xF0, wc[24]); RXG(0x78, wc[25]); RXG(0x3C, wc[26]); RXG(0x1E, wc[27]);
  RXG(0x0F, wc[28]); RXG(0xC7, wc[29]); RXG(0xA3, wc[30]); RXG(0x91, wc[31]);

#undef RXG

  // ---- <Z_7> after 4 chains: sign = (-1)^parity(j & 0x88) -> lane bits 1,5
  float mag = (sr[0] * sr[0] + si[0] * si[0]) + (sr[1] * sr[1] + si[1] * si[1])
            + (sr[2] * sr[2] + si[2] * si[2]) + (sr[3] * sr[3] + si[3] * si[3]);
  const int sgn = ((lane >> 5) ^ (lane >> 1)) & 1;
  float e = sgn ? -mag : mag;
#pragma unroll
  for (int off = 32; off > 0; off >>= 1)
    e += __shfl_xor(e, off, 64);

  if (lane == 0)
    out[((b * 4 + oc) * 64 + ph) * 64 + pw] = e;
}

} // namespace

extern "C" void kernel_launch(void* const* d_in, const int* in_sizes, int n_in,
                              void* d_out, int out_size, void* d_ws, size_t ws_size,
                              hipStream_t stream) {
  const float* x   = (const float*)d_in[0];   // 2*2*128*128 = 65536
  const float* wts = (const float*)d_in[1];   // 4*4*8 = 128
  float* out = (float*)d_out;                 // 2*4*64*64 = 32768
  qconv_kernel<<<8192, 256, 0, stream>>>(x, wts, out);
}

// Round 4
// 57.074 us; speedup vs baseline: 3.1330x; 2.3193x over previous
//
#include <hip/hip_runtime.h>
#include <math.h>

// Quanvolutional layer, closed form.
//
// In the CNOT-relabeled frame (R1, verified), the circuit is
//   U = prod_k [ cos(th_k/2) I - i sin(th_k/2) X_{v_k} ],  X_v|j> = |j^v>,
// measured with Z_m, m = 0x88. All X_v commute and are diagonal in the
// Walsh-Hadamard basis (eigenvalue (-1)^{w.v}); |0..0> is uniform there, so
//   E = (1/256) sum_w cos( sum_{k in S} eps_k(w) th_k ),
//   S = {k : parity(v_k & m) = 1},  eps_k(w) = (-1)^{popc(w & v_k)}.
//
// Surviving gates: 18 weight gates (2+4+4+8 across the 4 layers — ALL of
// layer 3 survives) + 2 data gates (embed q0: v=0x80, th0 = x[b,0,2ph,2pw];
// embed q4: v=0x08, th4 = x[b,1,2ph,2pw]); the other 6 pixel angles cancel.
// Expanding the data angles:
//   E = Kcc cos0 cos4 + Kss sin0 sin4 + Ksc sin0 cos4 + Kcs cos0 sin4
// with per-oc coefficients (s0 = bit7 of w, s4 = bit3 of w):
//   Kcc =  (1/256) sum_w cos a_w
//   Kss = -(1/256) sum_w eps0 eps4 cos a_w
//   Ksc = -(1/256) sum_w eps0 sin a_w
//   Kcs = -(1/256) sum_w eps4 sin a_w
//   a_w = signed sum of the 18 weight angles.

namespace {

__constant__ const unsigned char GV[18] = {0x80, 0x08, 0xC0, 0x18, 0x0C, 0xC1,
                                           0xA0, 0x28, 0x0A, 0xC2, 0xF0, 0x78,
                                           0x3C, 0x1E, 0x0F, 0xC7, 0xA3, 0x91};
__constant__ const unsigned char GI[18] = {0, 4, 8, 11, 12, 15, 16, 18, 20, 22,
                                           24, 25, 26, 27, 28, 29, 30, 31};

__global__ __launch_bounds__(256) void qconv_kernel(
    const float* __restrict__ x,     // (2, 2, 128, 128) fp32
    const float* __restrict__ wts,   // (4, 4, 8) fp32
    float* __restrict__ out)         // (2, 4, 64, 64) fp32
{
  const int tid  = threadIdx.x;
  const int lane = tid & 63;
  const int wave = tid >> 6;

  __shared__ float K[4][4];          // [oc][cc,ss,sc,cs]

  // ---- phase A: coefficients (recomputed identically in every block).
  // wave = oc; lane handles w in {lane, lane+64, lane+128, lane+192}.
  {
    const int oc = wave;
    double scc = 0.0, sss = 0.0, ssc = 0.0, scs = 0.0;
#pragma unroll
    for (int j = 0; j < 4; ++j) {
      const int w = lane + 64 * j;
      double a = 0.0;
#pragma unroll
      for (int g = 0; g < 18; ++g) {
        const double th = (double)wts[oc * 32 + GI[g]];
        a += (__popc(w & GV[g]) & 1) ? -th : th;
      }
      double sa, ca;
      sincos(a, &sa, &ca);
      const int s0 = (w >> 7) & 1;
      const int s4 = (w >> 3) & 1;
      scc += ca;
      sss += (s0 == s4) ? -ca : ca;   // -eps0*eps4*ca
      ssc += s0 ? sa : -sa;           // -eps0*sa
      scs += s4 ? sa : -sa;           // -eps4*sa
    }
    // wave-level reduce (64 lanes)
#pragma unroll
    for (int off = 32; off > 0; off >>= 1) {
      scc += __shfl_xor(scc, off, 64);
      sss += __shfl_xor(sss, off, 64);
      ssc += __shfl_xor(ssc, off, 64);
      scs += __shfl_xor(scs, off, 64);
    }
    if (lane == 0) {
      K[oc][0] = (float)(scc * (1.0 / 256.0));
      K[oc][1] = (float)(sss * (1.0 / 256.0));
      K[oc][2] = (float)(ssc * (1.0 / 256.0));
      K[oc][3] = (float)(scs * (1.0 / 256.0));
    }
  }
  __syncthreads();

  // ---- phase B: one thread per patch.
  const int p  = blockIdx.x * 256 + tid;       // 8192 patches
  const int b  = p >> 12;
  const int ph = (p >> 6) & 63;
  const int pw = p & 63;

  const float th0 = x[((b * 2 + 0) * 128 + 2 * ph) * 128 + 2 * pw];
  const float th4 = x[((b * 2 + 1) * 128 + 2 * ph) * 128 + 2 * pw];
  float s0, c0, s4, c4;
  __sincosf(th0, &s0, &c0);
  __sincosf(th4, &s4, &c4);
  const float cc = c0 * c4, ss = s0 * s4, sc = s0 * c4, cs = c0 * s4;

#pragma unroll
  for (int oc = 0; oc < 4; ++oc) {
    out[((b * 4 + oc) * 64 + ph) * 64 + pw] =
        K[oc][0] * cc + K[oc][1] * ss + K[oc][2] * sc + K[oc][3] * cs;
  }
}

} // namespace

extern "C" void kernel_launch(void* const* d_in, const int* in_sizes, int n_in,
                              void* d_out, int out_size, void* d_ws, size_t ws_size,
                              hipStream_t stream) {
  const float* x   = (const float*)d_in[0];   // 2*2*128*128 = 65536
  const float* wts = (const float*)d_in[1];   // 4*4*8 = 128
  float* out = (float*)d_out;                 // 2*4*64*64 = 32768
  qconv_kernel<<<32, 256, 0, stream>>>(x, wts, out);
}

// Round 5
// 55.197 us; speedup vs baseline: 3.2395x; 1.0340x over previous
//
#include <hip/hip_runtime.h>
#include <math.h>

// Quanvolutional layer, closed form.
//
// In the CNOT-relabeled frame (R1, verified), the circuit is
//   U = prod_k [ cos(th_k/2) I - i sin(th_k/2) X_{v_k} ],  X_v|j> = |j^v>,
// measured with Z_m, m = 0x88. All X_v commute and are diagonal in the
// Walsh-Hadamard basis (eigenvalue (-1)^{w.v}); |0..0> is uniform there, so
//   E = (1/256) sum_w cos( sum_{k in S} eps_k(w) th_k ),
//   S = {k : parity(v_k & m) = 1},  eps_k(w) = (-1)^{popc(w & v_k)}.
//
// Surviving gates: 18 weight gates (2+4+4+8 per layer — all of layer 3) +
// 2 data gates (embed q0: v=0x80, th0 = x[b,0,2ph,2pw]; embed q4: v=0x08,
// th4 = x[b,1,2ph,2pw]); the other 6 pixel angles cancel exactly.
// Expanding the data angles:
//   E = Kcc cos0 cos4 + Kss sin0 sin4 + Ksc sin0 cos4 + Kcs cos0 sin4
// with per-oc coefficients (eps0 = bit7 of w, eps4 = bit3 of w):
//   Kcc =  (1/256) sum_w cos a_w          Kss = -(1/256) sum_w eps0 eps4 cos a_w
//   Ksc = -(1/256) sum_w eps0 sin a_w     Kcs = -(1/256) sum_w eps4 sin a_w
//   a_w = signed sum of the 18 weight angles.
//
// Perf note (R4): a_w accumulated in f64 (|a| up to ~113 rad; fp32 accum
// would cost ~1e-3 angle error), but sincos evaluated in f32 after exact
// f64 range reduction f = a/2pi - rint(a/2pi) — avoids the expensive
// software f64 sincos that dominated phase A.

namespace {

__constant__ const unsigned char GV[18] = {0x80, 0x08, 0xC0, 0x18, 0x0C, 0xC1,
                                           0xA0, 0x28, 0x0A, 0xC2, 0xF0, 0x78,
                                           0x3C, 0x1E, 0x0F, 0xC7, 0xA3, 0x91};
__constant__ const unsigned char GI[18] = {0, 4, 8, 11, 12, 15, 16, 18, 20, 22,
                                           24, 25, 26, 27, 28, 29, 30, 31};

__global__ __launch_bounds__(256) void qconv_kernel(
    const float* __restrict__ x,     // (2, 2, 128, 128) fp32
    const float* __restrict__ wts,   // (4, 4, 8) fp32
    float* __restrict__ out)         // (2, 4, 64, 64) fp32
{
  const int tid  = threadIdx.x;
  const int lane = tid & 63;
  const int wave = tid >> 6;

  __shared__ float K[4][4];          // [oc][cc,ss,sc,cs]

  // ---- phase A: coefficients (recomputed identically in every block).
  // wave = oc; lane handles w in {lane, lane+64, lane+128, lane+192}.
  {
    const int oc = wave;
    // hoist the 18 weight loads (wave-uniform addresses -> broadcast)
    double th[18];
#pragma unroll
    for (int g = 0; g < 18; ++g) th[g] = (double)wts[oc * 32 + GI[g]];

    float scc = 0.0f, sss = 0.0f, ssc = 0.0f, scs = 0.0f;
#pragma unroll
    for (int j = 0; j < 4; ++j) {
      const int w = lane + 64 * j;
      double a = 0.0;
#pragma unroll
      for (int g = 0; g < 18; ++g)
        a += (__popc(w & GV[g]) & 1) ? -th[g] : th[g];
      // exact-enough range reduction in f64, transcendental in f32
      const double r = a * 0.15915494309189535;      // a / 2pi
      const float  f = (float)(r - rint(r));         // fractional revolutions
      float sa, ca;
      __sincosf(6.283185307179586f * f, &sa, &ca);
      const int s0 = (w >> 7) & 1;
      const int s4 = (w >> 3) & 1;
      scc += ca;
      sss += (s0 == s4) ? -ca : ca;   // -eps0*eps4*ca
      ssc += s0 ? sa : -sa;           // -eps0*sa
      scs += s4 ? sa : -sa;           // -eps4*sa
    }
    // wave-level reduce (64 lanes)
#pragma unroll
    for (int off = 32; off > 0; off >>= 1) {
      scc += __shfl_xor(scc, off, 64);
      sss += __shfl_xor(sss, off, 64);
      ssc += __shfl_xor(ssc, off, 64);
      scs += __shfl_xor(scs, off, 64);
    }
    if (lane == 0) {
      K[oc][0] = scc * (1.0f / 256.0f);
      K[oc][1] = sss * (1.0f / 256.0f);
      K[oc][2] = ssc * (1.0f / 256.0f);
      K[oc][3] = scs * (1.0f / 256.0f);
    }
  }
  __syncthreads();

  // ---- phase B: one thread per patch.
  const int p  = blockIdx.x * 256 + tid;       // 8192 patches
  const int b  = p >> 12;
  const int ph = (p >> 6) & 63;
  const int pw = p & 63;

  const float th0 = x[((b * 2 + 0) * 128 + 2 * ph) * 128 + 2 * pw];
  const float th4 = x[((b * 2 + 1) * 128 + 2 * ph) * 128 + 2 * pw];
  float s0, c0, s4, c4;
  __sincosf(th0, &s0, &c0);
  __sincosf(th4, &s4, &c4);
  const float cc = c0 * c4, ss = s0 * s4, sc = s0 * c4, cs = c0 * s4;

#pragma unroll
  for (int oc = 0; oc < 4; ++oc) {
    out[((b * 4 + oc) * 64 + ph) * 64 + pw] =
        K[oc][0] * cc + K[oc][1] * ss + K[oc][2] * sc + K[oc][3] * cs;
  }
}

} // namespace

extern "C" void kernel_launch(void* const* d_in, const int* in_sizes, int n_in,
                              void* d_out, int out_size, void* d_ws, size_t ws_size,
                              hipStream_t stream) {
  const float* x   = (const float*)d_in[0];   // 2*2*128*128 = 65536
  const float* wts = (const float*)d_in[1];   // 4*4*8 = 128
  float* out = (float*)d_out;                 // 2*4*64*64 = 32768
  qconv_kernel<<<32, 256, 0, stream>>>(x, wts, out);
}